// Round 1
// baseline (1315.451 us; speedup 1.0000x reference)
//
#include <hip/hip_runtime.h>

#define D 256
#define BM 64
#define KB 32

__device__ __forceinline__ void fma4(float4& a, float s, const float4& w) {
    a.x = fmaf(s, w.x, a.x);
    a.y = fmaf(s, w.y, a.y);
    a.z = fmaf(s, w.z, a.z);
    a.w = fmaf(s, w.w, a.w);
}

// ---- CSR build ---------------------------------------------------------

__global__ void k_hist(const int* __restrict__ dst, int* __restrict__ deg, int E) {
    int e = blockIdx.x * blockDim.x + threadIdx.x;
    if (e < E) atomicAdd(&deg[dst[e]], 1);
}

__global__ void k_block_sums(const int* __restrict__ deg, int* __restrict__ bsum, int N) {
    __shared__ int s[256];
    int t = threadIdx.x;
    int base = blockIdx.x * 1024 + t * 4;
    int sum = 0;
#pragma unroll
    for (int j = 0; j < 4; ++j) {
        int i = base + j;
        if (i < N) sum += deg[i];
    }
    s[t] = sum;
    __syncthreads();
    for (int off = 128; off > 0; off >>= 1) {
        if (t < off) s[t] += s[t + off];
        __syncthreads();
    }
    if (t == 0) bsum[blockIdx.x] = s[0];
}

// single block, 128 threads, NB <= 128
__global__ void k_scan_bsums(const int* __restrict__ bsum, int* __restrict__ boffs, int NB) {
    __shared__ int s[128];
    int t = threadIdx.x;
    int v = (t < NB) ? bsum[t] : 0;
    s[t] = v;
    __syncthreads();
    for (int off = 1; off < 128; off <<= 1) {
        int u = (t >= off) ? s[t - off] : 0;
        __syncthreads();
        s[t] += u;
        __syncthreads();
    }
    if (t < NB) boffs[t] = s[t] - v;  // exclusive block offset
}

__global__ void k_scan_final(const int* __restrict__ deg, const int* __restrict__ boffs,
                             int* __restrict__ row_ptr, int* __restrict__ cursor,
                             int N, int E) {
    __shared__ int s[256];
    int t = threadIdx.x;
    int base = blockIdx.x * 1024 + t * 4;
    int d[4];
    int sum = 0;
#pragma unroll
    for (int j = 0; j < 4; ++j) {
        int i = base + j;
        d[j] = (i < N) ? deg[i] : 0;
        sum += d[j];
    }
    s[t] = sum;
    __syncthreads();
    for (int off = 1; off < 256; off <<= 1) {
        int u = (t >= off) ? s[t - off] : 0;
        __syncthreads();
        s[t] += u;
        __syncthreads();
    }
    int p = boffs[blockIdx.x] + s[t] - sum;  // exclusive prefix for this thread
#pragma unroll
    for (int j = 0; j < 4; ++j) {
        int i = base + j;
        if (i < N) {
            row_ptr[i] = p;
            cursor[i]  = p;
            p += d[j];
        }
    }
    if (blockIdx.x == 0 && t == 0) row_ptr[N] = E;
}

__global__ void k_scatter(const int* __restrict__ src, const int* __restrict__ dst,
                          const float* __restrict__ vals, int* __restrict__ cursor,
                          int* __restrict__ csr_src, float* __restrict__ csr_val, int E) {
    int e = blockIdx.x * blockDim.x + threadIdx.x;
    if (e < E) {
        int d = dst[e];
        int pos = atomicAdd(&cursor[d], 1);
        csr_src[pos] = src[e];
        csr_val[pos] = vals[e];
    }
}

// ---- aggregation: one wave per dst node, agg = A @ x into d_out --------

__global__ void k_agg(const float* __restrict__ x, const int* __restrict__ row_ptr,
                      const int* __restrict__ csr_src, const float* __restrict__ csr_val,
                      float* __restrict__ out, int N) {
    int lane = threadIdx.x & 63;
    int n = blockIdx.x * 4 + (threadIdx.x >> 6);
    if (n >= N) return;
    int beg = row_ptr[n], end = row_ptr[n + 1];
    float4 acc = make_float4(0.f, 0.f, 0.f, 0.f);
    int i = beg;
    for (; i + 2 <= end; i += 2) {
        int s0 = csr_src[i];
        int s1 = csr_src[i + 1];
        float v0 = csr_val[i];
        float v1 = csr_val[i + 1];
        float4 a = reinterpret_cast<const float4*>(x + (size_t)s0 * D)[lane];
        float4 b = reinterpret_cast<const float4*>(x + (size_t)s1 * D)[lane];
        fma4(acc, v0, a);
        fma4(acc, v1, b);
    }
    if (i < end) {
        int s0 = csr_src[i];
        float v0 = csr_val[i];
        float4 a = reinterpret_cast<const float4*>(x + (size_t)s0 * D)[lane];
        fma4(acc, v0, a);
    }
    reinterpret_cast<float4*>(out + (size_t)n * D)[lane] = acc;
}

// ---- fused dense: out = agg @ Wn + x @ Wo + bias (agg lives in out) ----

__global__ __launch_bounds__(256) void k_gemm(const float* __restrict__ x,
                                              const float* __restrict__ wn,
                                              const float* __restrict__ wo,
                                              const float* __restrict__ bias,
                                              float* __restrict__ out, int N) {
    __shared__ float sW[KB][D];         // 32 KB
    __shared__ float sInT[KB][BM + 4];  // transposed input chunk, pad->stride 68 floats

    int t = threadIdx.x;
    int c = t & 63;   // col group: cols c*4 .. c*4+3
    int r = t >> 6;   // 0..3 -> rows r*16 .. r*16+15
    int rowBase = blockIdx.x * BM;

    float4 acc[16];
#pragma unroll
    for (int m = 0; m < 16; ++m) acc[m] = make_float4(0.f, 0.f, 0.f, 0.f);

#pragma unroll
    for (int phase = 0; phase < 2; ++phase) {
        const float* src = (phase == 0) ? out : x;
        const float* w   = (phase == 0) ? wn  : wo;
        for (int k0 = 0; k0 < D; k0 += KB) {
            __syncthreads();  // protect previous chunk's reads
            // stage input tile, transposed: sInT[kk][row]
#pragma unroll
            for (int it = 0; it < 2; ++it) {
                int idx = t + it * 256;
                int lrow = idx >> 3;
                int g = idx & 7;
                int grow = rowBase + lrow;
                if (grow >= N) grow = N - 1;
                float4 v = *reinterpret_cast<const float4*>(src + (size_t)grow * D + k0 + g * 4);
                sInT[g * 4 + 0][lrow] = v.x;
                sInT[g * 4 + 1][lrow] = v.y;
                sInT[g * 4 + 2][lrow] = v.z;
                sInT[g * 4 + 3][lrow] = v.w;
            }
            // stage W chunk: sW[kk][0..255]
#pragma unroll
            for (int it = 0; it < 8; ++it) {
                int idx = t + it * 256;
                int kk = idx >> 6;
                int cg = idx & 63;
                *reinterpret_cast<float4*>(&sW[kk][cg * 4]) =
                    *reinterpret_cast<const float4*>(w + (size_t)(k0 + kk) * D + cg * 4);
            }
            __syncthreads();
#pragma unroll 8
            for (int kk = 0; kk < KB; ++kk) {
                float4 wv = *reinterpret_cast<const float4*>(&sW[kk][c * 4]);
#pragma unroll
                for (int mq = 0; mq < 4; ++mq) {
                    float4 av = *reinterpret_cast<const float4*>(&sInT[kk][r * 16 + mq * 4]);
                    fma4(acc[mq * 4 + 0], av.x, wv);
                    fma4(acc[mq * 4 + 1], av.y, wv);
                    fma4(acc[mq * 4 + 2], av.z, wv);
                    fma4(acc[mq * 4 + 3], av.w, wv);
                }
            }
        }
    }

    float4 bv = *reinterpret_cast<const float4*>(bias + c * 4);
#pragma unroll
    for (int m = 0; m < 16; ++m) {
        int grow = rowBase + r * 16 + m;
        if (grow < N) {
            float4 o = acc[m];
            o.x += bv.x; o.y += bv.y; o.z += bv.z; o.w += bv.w;
            *reinterpret_cast<float4*>(out + (size_t)grow * D + c * 4) = o;
        }
    }
}

// ---- launch ------------------------------------------------------------

extern "C" void kernel_launch(void* const* d_in, const int* in_sizes, int n_in,
                              void* d_out, int out_size, void* d_ws, size_t ws_size,
                              hipStream_t stream) {
    const float* x    = (const float*)d_in[0];
    const int*   esrc = (const int*)d_in[1];
    const int*   edst = (const int*)d_in[2];
    const float* vals = (const float*)d_in[3];
    const float* wn   = (const float*)d_in[4];
    const float* wo   = (const float*)d_in[5];
    const float* bias = (const float*)d_in[6];
    float* out = (float*)d_out;

    int N = in_sizes[0] / D;
    int E = in_sizes[1];

    int* deg     = (int*)d_ws;          // N
    int* row_ptr = deg + N;             // N+1
    int* cursor  = row_ptr + N + 1;     // N
    int* bsum    = cursor + N;          // 128
    int* boffs   = bsum + 128;          // 128
    int* csr_src = boffs + 128;         // E
    float* csr_val = (float*)(csr_src + E);  // E

    int NB = (N + 1023) / 1024;  // 98 for N=100000

    hipMemsetAsync(deg, 0, (size_t)N * sizeof(int), stream);
    k_hist<<<(E + 255) / 256, 256, 0, stream>>>(edst, deg, E);
    k_block_sums<<<NB, 256, 0, stream>>>(deg, bsum, N);
    k_scan_bsums<<<1, 128, 0, stream>>>(bsum, boffs, NB);
    k_scan_final<<<NB, 256, 0, stream>>>(deg, boffs, row_ptr, cursor, N, E);
    k_scatter<<<(E + 255) / 256, 256, 0, stream>>>(esrc, edst, vals, cursor, csr_src, csr_val, E);
    k_agg<<<(N + 3) / 4, 256, 0, stream>>>(x, row_ptr, csr_src, csr_val, out, N);
    k_gemm<<<(N + BM - 1) / BM, 256, 0, stream>>>(x, wn, wo, bias, out, N);
}

// Round 5
// 976.276 us; speedup vs baseline: 1.3474x; 1.3474x over previous
//
#include <hip/hip_runtime.h>
#include <hip/hip_fp16.h>

#define DN 256
#define KTOT 512
#define GBM 128
#define GBK 64

typedef __attribute__((ext_vector_type(8))) short bf16x8;
typedef __attribute__((ext_vector_type(8))) unsigned short u16x8;
typedef __attribute__((ext_vector_type(4))) float f32x4;

__device__ __forceinline__ unsigned short f2b(float f) {
    unsigned u = __float_as_uint(f);
    u += 0x7FFF + ((u >> 16) & 1);   // round-to-nearest-even
    return (unsigned short)(u >> 16);
}
__device__ __forceinline__ float b2f(unsigned short b) {
    return __uint_as_float(((unsigned)b) << 16);
}

// ---- CSR build ---------------------------------------------------------

__global__ void k_hist(const int* __restrict__ dst, int* __restrict__ deg, int E) {
    int e = blockIdx.x * blockDim.x + threadIdx.x;
    if (e < E) atomicAdd(&deg[dst[e]], 1);
}

__global__ void k_block_sums(const int* __restrict__ deg, int* __restrict__ bsum, int N) {
    __shared__ int s[256];
    int t = threadIdx.x;
    int base = blockIdx.x * 1024 + t * 4;
    int sum = 0;
#pragma unroll
    for (int j = 0; j < 4; ++j) {
        int i = base + j;
        if (i < N) sum += deg[i];
    }
    s[t] = sum;
    __syncthreads();
    for (int off = 128; off > 0; off >>= 1) {
        if (t < off) s[t] += s[t + off];
        __syncthreads();
    }
    if (t == 0) bsum[blockIdx.x] = s[0];
}

__global__ void k_scan_bsums(const int* __restrict__ bsum, int* __restrict__ boffs, int NB) {
    __shared__ int s[128];
    int t = threadIdx.x;
    int v = (t < NB) ? bsum[t] : 0;
    s[t] = v;
    __syncthreads();
    for (int off = 1; off < 128; off <<= 1) {
        int u = (t >= off) ? s[t - off] : 0;
        __syncthreads();
        s[t] += u;
        __syncthreads();
    }
    if (t < NB) boffs[t] = s[t] - v;
}

__global__ void k_scan_final(const int* __restrict__ deg, const int* __restrict__ boffs,
                             int* __restrict__ row_ptr, int* __restrict__ cursor,
                             int N, int E) {
    __shared__ int s[256];
    int t = threadIdx.x;
    int base = blockIdx.x * 1024 + t * 4;
    int d[4];
    int sum = 0;
#pragma unroll
    for (int j = 0; j < 4; ++j) {
        int i = base + j;
        d[j] = (i < N) ? deg[i] : 0;
        sum += d[j];
    }
    s[t] = sum;
    __syncthreads();
    for (int off = 1; off < 256; off <<= 1) {
        int u = (t >= off) ? s[t - off] : 0;
        __syncthreads();
        s[t] += u;
        __syncthreads();
    }
    int p = boffs[blockIdx.x] + s[t] - sum;
#pragma unroll
    for (int j = 0; j < 4; ++j) {
        int i = base + j;
        if (i < N) {
            row_ptr[i] = p;
            cursor[i]  = p;
            p += d[j];
        }
    }
    if (blockIdx.x == 0 && t == 0) row_ptr[N] = E;
}

__global__ void k_scatter(const int* __restrict__ src, const int* __restrict__ dst,
                          const float* __restrict__ vals, int* __restrict__ cursor,
                          long long* __restrict__ csr, int E) {
    int e = blockIdx.x * blockDim.x + threadIdx.x;
    if (e < E) {
        int d = dst[e];
        int pos = atomicAdd(&cursor[d], 1);
        long long packed = (long long)(unsigned)src[e] |
                           ((long long)__float_as_int(vals[e]) << 32);
        csr[pos] = packed;
    }
}

// ---- conversions -------------------------------------------------------

// x fp32 -> fp16 (RN), 8 elems/thread
__global__ void k_cvt_x(const float* __restrict__ x, __half* __restrict__ xh, int total8) {
    int t = blockIdx.x * blockDim.x + threadIdx.x;
    if (t >= total8) return;
    const float4* p = (const float4*)(x + (size_t)t * 8);
    float4 a = p[0], b = p[1];
    __half h[8];
    h[0] = __float2half(a.x); h[1] = __float2half(a.y);
    h[2] = __float2half(a.z); h[3] = __float2half(a.w);
    h[4] = __float2half(b.x); h[5] = __float2half(b.y);
    h[6] = __float2half(b.z); h[7] = __float2half(b.w);
    *(u16x8*)(xh + (size_t)t * 8) = *(const u16x8*)h;
}

// Wcat[512][256] -> transposed split bf16: wt_hi/wt_lo layout [n][k]
__global__ void k_cvt_w(const float* __restrict__ wn, const float* __restrict__ wo,
                        unsigned short* __restrict__ wth, unsigned short* __restrict__ wtl) {
    int t = blockIdx.x * blockDim.x + threadIdx.x;  // t = k*256 + n, k in [0,512)
    int k = t >> 8;
    int n = t & 255;
    float v = (k < 256) ? wn[k * 256 + n] : wo[(k - 256) * 256 + n];
    unsigned short h = f2b(v);
    unsigned short l = f2b(v - b2f(h));
    wth[(size_t)n * KTOT + k] = h;
    wtl[(size_t)n * KTOT + k] = l;
}

// ---- aggregation: agg = A @ x, one wave per dst node -------------------

__global__ void k_agg_f16(const __half* __restrict__ xh, const int* __restrict__ row_ptr,
                          const long long* __restrict__ csr, float* __restrict__ out, int N) {
    int lane = threadIdx.x & 63;
    int n = blockIdx.x * 4 + (threadIdx.x >> 6);
    if (n >= N) return;
    int beg = row_ptr[n], end = row_ptr[n + 1];
    float ax = 0.f, ay = 0.f, az = 0.f, aw = 0.f;
    int i = beg;
    for (; i + 4 <= end; i += 4) {
        long long e0 = csr[i], e1 = csr[i + 1], e2 = csr[i + 2], e3 = csr[i + 3];
        const __half2* p0 = (const __half2*)(xh + (size_t)(int)e0 * DN) + lane * 2;
        const __half2* p1 = (const __half2*)(xh + (size_t)(int)e1 * DN) + lane * 2;
        const __half2* p2 = (const __half2*)(xh + (size_t)(int)e2 * DN) + lane * 2;
        const __half2* p3 = (const __half2*)(xh + (size_t)(int)e3 * DN) + lane * 2;
        __half2 a0 = p0[0], b0 = p0[1];
        __half2 a1 = p1[0], b1 = p1[1];
        __half2 a2 = p2[0], b2 = p2[1];
        __half2 a3 = p3[0], b3 = p3[1];
        float v0 = __int_as_float((int)(e0 >> 32));
        float v1 = __int_as_float((int)(e1 >> 32));
        float v2 = __int_as_float((int)(e2 >> 32));
        float v3 = __int_as_float((int)(e3 >> 32));
        ax = fmaf(v0, __half2float(a0.x), ax); ay = fmaf(v0, __half2float(a0.y), ay);
        az = fmaf(v0, __half2float(b0.x), az); aw = fmaf(v0, __half2float(b0.y), aw);
        ax = fmaf(v1, __half2float(a1.x), ax); ay = fmaf(v1, __half2float(a1.y), ay);
        az = fmaf(v1, __half2float(b1.x), az); aw = fmaf(v1, __half2float(b1.y), aw);
        ax = fmaf(v2, __half2float(a2.x), ax); ay = fmaf(v2, __half2float(a2.y), ay);
        az = fmaf(v2, __half2float(b2.x), az); aw = fmaf(v2, __half2float(b2.y), aw);
        ax = fmaf(v3, __half2float(a3.x), ax); ay = fmaf(v3, __half2float(a3.y), ay);
        az = fmaf(v3, __half2float(b3.x), az); aw = fmaf(v3, __half2float(b3.y), aw);
    }
    for (; i < end; ++i) {
        long long e0 = csr[i];
        const __half2* p0 = (const __half2*)(xh + (size_t)(int)e0 * DN) + lane * 2;
        __half2 a0 = p0[0], b0 = p0[1];
        float v0 = __int_as_float((int)(e0 >> 32));
        ax = fmaf(v0, __half2float(a0.x), ax); ay = fmaf(v0, __half2float(a0.y), ay);
        az = fmaf(v0, __half2float(b0.x), az); aw = fmaf(v0, __half2float(b0.y), aw);
    }
    float4 o = make_float4(ax, ay, az, aw);
    ((float4*)(out + (size_t)n * DN))[lane] = o;
}

__global__ void k_agg_f32(const float* __restrict__ x, const int* __restrict__ row_ptr,
                          const long long* __restrict__ csr, float* __restrict__ out, int N) {
    int lane = threadIdx.x & 63;
    int n = blockIdx.x * 4 + (threadIdx.x >> 6);
    if (n >= N) return;
    int beg = row_ptr[n], end = row_ptr[n + 1];
    float4 acc = make_float4(0.f, 0.f, 0.f, 0.f);
    int i = beg;
    for (; i + 2 <= end; i += 2) {
        long long e0 = csr[i], e1 = csr[i + 1];
        float4 a = ((const float4*)(x + (size_t)(int)e0 * DN))[lane];
        float4 b = ((const float4*)(x + (size_t)(int)e1 * DN))[lane];
        float v0 = __int_as_float((int)(e0 >> 32));
        float v1 = __int_as_float((int)(e1 >> 32));
        acc.x = fmaf(v0, a.x, acc.x); acc.y = fmaf(v0, a.y, acc.y);
        acc.z = fmaf(v0, a.z, acc.z); acc.w = fmaf(v0, a.w, acc.w);
        acc.x = fmaf(v1, b.x, acc.x); acc.y = fmaf(v1, b.y, acc.y);
        acc.z = fmaf(v1, b.z, acc.z); acc.w = fmaf(v1, b.w, acc.w);
    }
    if (i < end) {
        long long e0 = csr[i];
        float4 a = ((const float4*)(x + (size_t)(int)e0 * DN))[lane];
        float v0 = __int_as_float((int)(e0 >> 32));
        acc.x = fmaf(v0, a.x, acc.x); acc.y = fmaf(v0, a.y, acc.y);
        acc.z = fmaf(v0, a.z, acc.z); acc.w = fmaf(v0, a.w, acc.w);
    }
    ((float4*)(out + (size_t)n * DN))[lane] = acc;
}

// ---- MFMA split-bf16 GEMM: out = [agg|x] @ Wcat + bias -----------------
// block: 128 rows x 256 cols, 512 threads (8 waves, 2x4), wave tile 64x64

__device__ __forceinline__ void cvt8(const float4 a, const float4 b, u16x8& h, u16x8& lo) {
    float f[8] = {a.x, a.y, a.z, a.w, b.x, b.y, b.z, b.w};
#pragma unroll
    for (int j = 0; j < 8; ++j) {
        unsigned short hb = f2b(f[j]);
        h[j] = hb;
        lo[j] = f2b(f[j] - b2f(hb));
    }
}

__global__ __launch_bounds__(512) void k_gemm(const float* __restrict__ x,
                                              const unsigned short* __restrict__ wth,
                                              const unsigned short* __restrict__ wtl,
                                              const float* __restrict__ bias,
                                              float* __restrict__ out, int N) {
    __shared__ unsigned short Ah[GBM * GBK];   // 16 KB, XOR-swizzled rows of 128B
    __shared__ unsigned short Al[GBM * GBK];   // 16 KB

    int t = threadIdx.x;
    int l = t & 63;
    int wid = t >> 6;
    int wr = wid >> 2;      // 0..1 : row half
    int wc = wid & 3;       // 0..3 : col quarter
    int r0 = blockIdx.x * GBM;
    int lr = l & 15;        // lane row/col within fragment
    int lg = l >> 4;        // lane k-group

    f32x4 acc[4][4];
#pragma unroll
    for (int m = 0; m < 4; ++m)
#pragma unroll
        for (int n = 0; n < 4; ++n) acc[m][n] = (f32x4)(0.f);

    int srow = t >> 2;      // 0..127 staging row
    int sseg = t & 3;       // 0..3  staging 16-elem segment

#pragma unroll 1
    for (int c = 0; c < 8; ++c) {
        int k0 = c * GBK;
        const float* src = (k0 < 256) ? out : x;
        int kc = k0 & 255;
        __syncthreads();
        {
            int grow = r0 + srow;
            if (grow >= N) grow = N - 1;
            const float4* p = (const float4*)(src + (size_t)grow * DN + kc + sseg * 16);
            float4 v0 = p[0], v1 = p[1], v2 = p[2], v3 = p[3];
            u16x8 h0, l0, h1, l1;
            cvt8(v0, v1, h0, l0);
            cvt8(v2, v3, h1, l1);
            int kg0 = sseg * 2, kg1 = sseg * 2 + 1;
            int rb = srow * 128;
            int sw = (srow & 7) << 4;
            *(u16x8*)((char*)Ah + rb + (((kg0 << 4)) ^ sw)) = h0;
            *(u16x8*)((char*)Al + rb + (((kg0 << 4)) ^ sw)) = l0;
            *(u16x8*)((char*)Ah + rb + (((kg1 << 4)) ^ sw)) = h1;
            *(u16x8*)((char*)Al + rb + (((kg1 << 4)) ^ sw)) = l1;
        }
        __syncthreads();
#pragma unroll
        for (int ks = 0; ks < 2; ++ks) {
            bf16x8 ah[4], al[4], bh[4], bl[4];
            int kg = ks * 4 + lg;
#pragma unroll
            for (int m = 0; m < 4; ++m) {
                int rl = wr * 64 + m * 16 + lr;
                int off = rl * 128 + (((kg << 4)) ^ ((rl & 7) << 4));
                ah[m] = *(const bf16x8*)((const char*)Ah + off);
                al[m] = *(const bf16x8*)((const char*)Al + off);
            }
#pragma unroll
            for (int n = 0; n < 4; ++n) {
                int col = wc * 64 + n * 16 + lr;
                size_t e = (size_t)col * KTOT + k0 + ks * 32 + lg * 8;
                bh[n] = *(const bf16x8*)(wth + e);
                bl[n] = *(const bf16x8*)(wtl + e);
            }
#pragma unroll
            for (int m = 0; m < 4; ++m)
#pragma unroll
                for (int n = 0; n < 4; ++n) {
                    acc[m][n] = __builtin_amdgcn_mfma_f32_16x16x32_bf16(ah[m], bh[n], acc[m][n], 0, 0, 0);
                    acc[m][n] = __builtin_amdgcn_mfma_f32_16x16x32_bf16(ah[m], bl[n], acc[m][n], 0, 0, 0);
                    acc[m][n] = __builtin_amdgcn_mfma_f32_16x16x32_bf16(al[m], bh[n], acc[m][n], 0, 0, 0);
                }
        }
    }

    float bv[4];
#pragma unroll
    for (int n = 0; n < 4; ++n) bv[n] = bias[wc * 64 + n * 16 + lr];

#pragma unroll
    for (int m = 0; m < 4; ++m) {
#pragma unroll
        for (int j = 0; j < 4; ++j) {
            int grow = r0 + wr * 64 + m * 16 + lg * 4 + j;
            if (grow < N) {
                float* orow = out + (size_t)grow * DN + wc * 64;
#pragma unroll
                for (int n = 0; n < 4; ++n) orow[n * 16 + lr] = acc[m][n][j] + bv[n];
            }
        }
    }
}

// ---- launch ------------------------------------------------------------

extern "C" void kernel_launch(void* const* d_in, const int* in_sizes, int n_in,
                              void* d_out, int out_size, void* d_ws, size_t ws_size,
                              hipStream_t stream) {
    const float* x    = (const float*)d_in[0];
    const int*   esrc = (const int*)d_in[1];
    const int*   edst = (const int*)d_in[2];
    const float* vals = (const float*)d_in[3];
    const float* wn   = (const float*)d_in[4];
    const float* wo   = (const float*)d_in[5];
    const float* bias = (const float*)d_in[6];
    float* out = (float*)d_out;

    int N = in_sizes[0] / DN;
    int E = in_sizes[1];

    char* ws = (char*)d_ws;
    size_t off = 0;
    auto alloc = [&](size_t bytes) { void* p = ws + off; off = (off + bytes + 255) & ~(size_t)255; return p; };

    int* deg      = (int*)alloc((size_t)N * 4);
    int* row_ptr  = (int*)alloc((size_t)(N + 1) * 4);
    int* cursor   = (int*)alloc((size_t)N * 4);
    int* bsum     = (int*)alloc(512);
    int* boffs    = (int*)alloc(512);
    long long* csr = (long long*)alloc((size_t)E * 8);
    unsigned short* wth = (unsigned short*)alloc((size_t)DN * KTOT * 2);
    unsigned short* wtl = (unsigned short*)alloc((size_t)DN * KTOT * 2);
    size_t xh_bytes = (size_t)N * DN * 2;
    bool use_f16 = (off + xh_bytes) <= ws_size;
    __half* xh = use_f16 ? (__half*)alloc(xh_bytes) : nullptr;

    int NB = (N + 1023) / 1024;

    hipMemsetAsync(deg, 0, (size_t)N * 4, stream);
    k_cvt_w<<<(KTOT * DN) / 256, 256, 0, stream>>>(wn, wo, wth, wtl);
    if (use_f16) {
        int total8 = N * DN / 8;
        k_cvt_x<<<(total8 + 255) / 256, 256, 0, stream>>>(x, xh, total8);
    }
    k_hist<<<(E + 255) / 256, 256, 0, stream>>>(edst, deg, E);
    k_block_sums<<<NB, 256, 0, stream>>>(deg, bsum, N);
    k_scan_bsums<<<1, 128, 0, stream>>>(bsum, boffs, NB);
    k_scan_final<<<NB, 256, 0, stream>>>(deg, boffs, row_ptr, cursor, N, E);
    k_scatter<<<(E + 255) / 256, 256, 0, stream>>>(esrc, edst, vals, cursor, csr, E);
    if (use_f16)
        k_agg_f16<<<(N + 3) / 4, 256, 0, stream>>>(xh, row_ptr, csr, out, N);
    else
        k_agg_f32<<<(N + 3) / 4, 256, 0, stream>>>(x, row_ptr, csr, out, N);
    k_gemm<<<(N + GBM - 1) / GBM, 512, 0, stream>>>(x, wth, wtl, bias, out, N);
}